// Round 7
// baseline (343.612 us; speedup 1.0000x reference)
//
#include <hip/hip_runtime.h>

typedef __bf16 bfv8 __attribute__((ext_vector_type(8)));
typedef float f32x4 __attribute__((ext_vector_type(4)));
typedef short shortv8 __attribute__((ext_vector_type(8)));

__device__ __forceinline__ float b2f(unsigned short u) {
  unsigned int v = ((unsigned int)u) << 16;
  float f;
  __builtin_memcpy(&f, &v, 4);
  return f;
}
__device__ __forceinline__ unsigned short f2b(float f) {
  unsigned int u;
  __builtin_memcpy(&u, &f, 4);
  u += 0x7fffu + ((u >> 16) & 1u);
  return (unsigned short)(u >> 16);
}

// ---------------- dtype probe (x): f32-as-bf16 shows ~48% absurd exponents ----
__global__ void probe_kernel(const unsigned short* __restrict__ x, int* __restrict__ flag) {
  int lane = threadIdx.x;  // 64 threads
  int cnt = 0;
  for (int i = lane; i < 4096; i += 64) {
    unsigned int e = (x[i] >> 7) & 0xffu;
    if (e >= 0x86u) cnt++;  // |val| >= 128
  }
#pragma unroll
  for (int off = 1; off < 64; off <<= 1) cnt += __shfl_xor(cnt, off, 64);
  if (lane == 0) *flag = (cnt > 100) ? 1 : 0;
}

// ---------------- canonicalize the 12 float param tensors to bf16 ----------------
// Wl1@0 bl1@65536 Wr1@65792 br1@131328 att1@131584 bias1@131840
// Wl2@132096 bl2@136192 Wr2@136208 br2@140304 att2@140320 bias2@140336  total 140352
#define P_TOT 140352
__global__ __launch_bounds__(256) void conv_params_kernel(
    const void* p0, const void* p1, const void* p2, const void* p3,
    const void* p4, const void* p5, const void* p6, const void* p7,
    const void* p8, const void* p9, const void* p10, const void* p11,
    unsigned short* __restrict__ dst, const int* __restrict__ flagp) {
  int i = blockIdx.x * 256 + threadIdx.x;
  if (i >= P_TOT) return;
  const int offs[13] = {0, 65536, 65792, 131328, 131584, 131840, 132096,
                        136192, 136208, 140304, 140320, 140336, P_TOT};
  const void* ptrs[12] = {p0, p1, p2, p3, p4, p5, p6, p7, p8, p9, p10, p11};
  int flag = *flagp;
  int t = 0;
  while (i >= offs[t + 1]) t++;
  int local = i - offs[t];
  unsigned short v;
  if (flag) v = f2b(((const float*)ptrs[t])[local]);
  else v = ((const unsigned short*)ptrs[t])[local];
  dst[i] = v;
}

// ---------------- merged W transposes: WT1[n][k]=W1[k][n], WT2[n][k]=W2[k][n] ----
__global__ __launch_bounds__(256) void transpose_w_kernel(
    const unsigned short* __restrict__ Pc,
    unsigned short* __restrict__ WT1, unsigned short* __restrict__ WT2) {
  int idx = blockIdx.x * 256 + threadIdx.x;
  if (idx < 512 * 256) {
    int n = idx >> 8, k = idx & 255;
    WT1[idx] = (n < 256) ? Pc[0 + k * 256 + n]          // Wl1
                         : Pc[65792 + k * 256 + (n - 256)];  // Wr1
  } else {
    int j = idx - 512 * 256;
    if (j < 32 * 256) {
      int n = j >> 8, k = j & 255;
      WT2[j] = (n < 16) ? Pc[132096 + k * 16 + n]       // Wl2
                        : Pc[136208 + k * 16 + (n - 16)];    // Wr2
    }
  }
}

// ---------------- GEMM1: C[M,512] = X[M,256] @ [Wl1|Wr1] + bias (bf16 out)
// Reads raw x (f32 or bf16 per flag) directly; LDS-staged coalesced epilogue.
__global__ __launch_bounds__(256) void gemm1_kernel(
    const void* __restrict__ X, const int* __restrict__ flagp,
    const unsigned short* __restrict__ WT,
    const unsigned short* __restrict__ bl, const unsigned short* __restrict__ br,
    unsigned short* __restrict__ C, int M) {
  __shared__ unsigned short ltile[4][64 * 72];
  const int lane = threadIdx.x & 63;
  const int w = threadIdx.x >> 6;
  const int quad = lane >> 4;
  const int l16 = lane & 15;
  const int m_base = blockIdx.x * 128 + (w >> 1) * 64;
  const int n_base = blockIdx.y * 128 + (w & 1) * 64;
  const int fl = *flagp;

  f32x4 acc[4][4];
#pragma unroll
  for (int i = 0; i < 4; i++)
#pragma unroll
    for (int j = 0; j < 4; j++) acc[i][j] = (f32x4){0.f, 0.f, 0.f, 0.f};

  if (fl) {  // x is float32: load f32, convert to bf16 in-register
    const float* Xf = (const float*)X;
#pragma unroll
    for (int k0 = 0; k0 < 256; k0 += 32) {
      bfv8 a[4], b[4];
#pragma unroll
      for (int i = 0; i < 4; i++) {
        int row = m_base + 16 * i + l16;
        if (row >= M) row = M - 1;
        const float* p = Xf + (size_t)row * 256 + k0 + quad * 8;
        float4 f0 = *reinterpret_cast<const float4*>(p);
        float4 f1 = *reinterpret_cast<const float4*>(p + 4);
        union { bfv8 v; unsigned short us[8]; } pa;
        pa.us[0] = f2b(f0.x); pa.us[1] = f2b(f0.y);
        pa.us[2] = f2b(f0.z); pa.us[3] = f2b(f0.w);
        pa.us[4] = f2b(f1.x); pa.us[5] = f2b(f1.y);
        pa.us[6] = f2b(f1.z); pa.us[7] = f2b(f1.w);
        a[i] = pa.v;
      }
#pragma unroll
      for (int j = 0; j < 4; j++) {
        int col = n_base + 16 * j + l16;
        b[j] = *reinterpret_cast<const bfv8*>(WT + (size_t)col * 256 + k0 + quad * 8);
      }
#pragma unroll
      for (int i = 0; i < 4; i++)
#pragma unroll
        for (int j = 0; j < 4; j++)
          acc[i][j] = __builtin_amdgcn_mfma_f32_16x16x32_bf16(a[i], b[j], acc[i][j], 0, 0, 0);
    }
  } else {  // x already bf16
    const unsigned short* Xb = (const unsigned short*)X;
#pragma unroll
    for (int k0 = 0; k0 < 256; k0 += 32) {
      bfv8 a[4], b[4];
#pragma unroll
      for (int i = 0; i < 4; i++) {
        int row = m_base + 16 * i + l16;
        if (row >= M) row = M - 1;
        a[i] = *reinterpret_cast<const bfv8*>(Xb + (size_t)row * 256 + k0 + quad * 8);
      }
#pragma unroll
      for (int j = 0; j < 4; j++) {
        int col = n_base + 16 * j + l16;
        b[j] = *reinterpret_cast<const bfv8*>(WT + (size_t)col * 256 + k0 + quad * 8);
      }
#pragma unroll
      for (int i = 0; i < 4; i++)
#pragma unroll
        for (int j = 0; j < 4; j++)
          acc[i][j] = __builtin_amdgcn_mfma_f32_16x16x32_bf16(a[i], b[j], acc[i][j], 0, 0, 0);
    }
  }

  // epilogue: stage 64x64 bf16 tile in LDS (stride 72 breaks pow-2 conflicts),
  // then coalesced 16B row-major stores. Same-wave LDS -> no barrier needed.
  unsigned short* lt = ltile[w];
#pragma unroll
  for (int j = 0; j < 4; j++) {
    int col = n_base + 16 * j + l16;
    float bias = (col < 256) ? b2f(bl[col]) : b2f(br[col - 256]);
#pragma unroll
    for (int i = 0; i < 4; i++)
#pragma unroll
      for (int r = 0; r < 4; r++)
        lt[(16 * i + quad * 4 + r) * 72 + 16 * j + l16] = f2b(acc[i][j][r] + bias);
  }
#pragma unroll
  for (int pass = 0; pass < 8; pass++) {
    int row = pass * 8 + (lane >> 3);
    int colg = (lane & 7) * 8;
    shortv8 v = *reinterpret_cast<const shortv8*>(lt + row * 72 + colg);
    int grow = m_base + row;
    if (grow < M)
      *reinterpret_cast<shortv8*>(C + (size_t)grow * 512 + n_base + colg) = v;
  }
}

// ---------------- GEMM2: C2[M,32] = H[M,256] @ [Wl2|Wr2] + bias (f32 out)
__global__ __launch_bounds__(256) void gemm2_kernel(
    const unsigned short* __restrict__ H, const unsigned short* __restrict__ WT,
    const unsigned short* __restrict__ bl, const unsigned short* __restrict__ br,
    float* __restrict__ C, int M) {
  const int lane = threadIdx.x & 63;
  const int w = threadIdx.x >> 6;
  const int quad = lane >> 4;
  const int l16 = lane & 15;
  const int m_base = blockIdx.x * 256 + w * 64;

  f32x4 acc[4][2];
#pragma unroll
  for (int i = 0; i < 4; i++)
#pragma unroll
    for (int j = 0; j < 2; j++) acc[i][j] = (f32x4){0.f, 0.f, 0.f, 0.f};

#pragma unroll
  for (int k0 = 0; k0 < 256; k0 += 32) {
    bfv8 a[4], b[2];
#pragma unroll
    for (int i = 0; i < 4; i++) {
      int row = m_base + 16 * i + l16;
      if (row >= M) row = M - 1;
      a[i] = *reinterpret_cast<const bfv8*>(H + (size_t)row * 256 + k0 + quad * 8);
    }
#pragma unroll
    for (int j = 0; j < 2; j++) {
      int col = 16 * j + l16;
      b[j] = *reinterpret_cast<const bfv8*>(WT + (size_t)col * 256 + k0 + quad * 8);
    }
#pragma unroll
    for (int i = 0; i < 4; i++)
#pragma unroll
      for (int j = 0; j < 2; j++)
        acc[i][j] = __builtin_amdgcn_mfma_f32_16x16x32_bf16(a[i], b[j], acc[i][j], 0, 0, 0);
  }

#pragma unroll
  for (int j = 0; j < 2; j++) {
    int col = 16 * j + l16;
    float bias = (j == 0) ? b2f(bl[l16]) : b2f(br[l16]);
#pragma unroll
    for (int i = 0; i < 4; i++) {
#pragma unroll
      for (int r = 0; r < 4; r++) {
        int row = m_base + 16 * i + quad * 4 + r;
        if (row < M) C[(size_t)row * 32 + col] = acc[i][j][r] + bias;
      }
    }
  }
}

// ---------------- CSR build: count + 3-kernel multi-block scan + fill ----------------
__global__ __launch_bounds__(256) void count_kernel(const int* __restrict__ ei, int E, int Nn,
                                                    int* __restrict__ cnt) {
  int i = blockIdx.x * 256 + threadIdx.x;
  int total = E + Nn;
  if (i >= total) return;
  int d = (i < E) ? ei[E + i] : (i - E);
  if ((unsigned)d >= (unsigned)Nn) d = 0;
  atomicAdd(&cnt[d], 1);
}

__global__ __launch_bounds__(1024) void scan1_kernel(const int* __restrict__ cnt,
                                                     int* __restrict__ row_start,
                                                     int* __restrict__ blkTot, int Nn) {
  __shared__ int buf[1024];
  int t = threadIdx.x;
  int i = blockIdx.x * 1024 + t;
  int v = (i < Nn) ? cnt[i] : 0;
  buf[t] = v;
  __syncthreads();
  for (int off = 1; off < 1024; off <<= 1) {
    int x = (t >= off) ? buf[t - off] : 0;
    __syncthreads();
    buf[t] += x;
    __syncthreads();
  }
  if (i < Nn) row_start[i] = buf[t] - v;  // block-local exclusive
  if (t == 1023) blkTot[blockIdx.x] = buf[1023];
}

__global__ __launch_bounds__(64) void scan2_kernel(const int* __restrict__ blkTot,
                                                   int* __restrict__ blkOff, int nb,
                                                   int* __restrict__ row_start, int Nn,
                                                   int total) {
  int lane = threadIdx.x;  // nb <= 64
  int v = (lane < nb) ? blkTot[lane] : 0;
  int s = v;
#pragma unroll
  for (int off = 1; off < 64; off <<= 1) {
    int u = __shfl_up(s, off, 64);
    if (lane >= off) s += u;
  }
  if (lane < nb) blkOff[lane] = s - v;
  if (lane == 0) row_start[Nn] = total;
}

__global__ __launch_bounds__(1024) void scan3_kernel(int* __restrict__ row_start,
                                                     int* __restrict__ cursor,
                                                     const int* __restrict__ blkOff, int Nn) {
  int i = blockIdx.x * 1024 + threadIdx.x;
  if (i < Nn) {
    int val = row_start[i] + blkOff[blockIdx.x];
    row_start[i] = val;
    cursor[i] = val;
  }
}

__global__ __launch_bounds__(256) void fill_kernel(const int* __restrict__ ei, int E, int Nn,
                                                   int* __restrict__ cursor,
                                                   int* __restrict__ csr_src) {
  int i = blockIdx.x * 256 + threadIdx.x;
  int total = E + Nn;
  if (i >= total) return;
  int s, d;
  if (i < E) { s = ei[i]; d = ei[E + i]; } else { s = i - E; d = i - E; }
  if ((unsigned)d >= (unsigned)Nn) d = 0;
  if ((unsigned)s >= (unsigned)Nn) s = 0;
  int pos = atomicAdd(&cursor[d], 1);
  if ((unsigned)pos < (unsigned)total) csr_src[pos] = s;
}

// ---------------- layer-1 aggregation (direct exp, 2-deep pipeline) + tanh ----------------
// One wave per dst node; lane owns channels [4*lane, 4*lane+4), head = lane>>4.
__global__ __launch_bounds__(256) void agg1_kernel(
    const unsigned short* __restrict__ C1,    // [N,512]: 0-255 xl, 256-511 xr
    const unsigned short* __restrict__ att1,  // [256]
    const unsigned short* __restrict__ bias1, // [256]
    const int* __restrict__ row_start, const int* __restrict__ csr_src,
    unsigned short* __restrict__ H1,          // [N,256] bf16
    int Nn, int Etot) {
  int wid = blockIdx.x * 4 + (threadIdx.x >> 6);
  if (wid >= Nn) return;
  int lane = threadIdx.x & 63;
  int c0 = lane * 4;

  ushort4 a4 = *reinterpret_cast<const ushort4*>(att1 + c0);
  float at0 = b2f(a4.x), at1 = b2f(a4.y), at2 = b2f(a4.z), at3 = b2f(a4.w);
  ushort4 r4 = *reinterpret_cast<const ushort4*>(C1 + (size_t)wid * 512 + 256 + c0);
  float xr0 = b2f(r4.x), xr1 = b2f(r4.y), xr2 = b2f(r4.z), xr3 = b2f(r4.w);

  float denom = 0.f, a0 = 0.f, a1 = 0.f, a2 = 0.f, a3 = 0.f;
  int beg = row_start[wid], end = row_start[wid + 1];
  if (beg < 0) beg = 0;
  if (end < beg || end - beg > Etot) end = beg;
  int n = end - beg;

  ushort4 cur0 = make_ushort4(0, 0, 0, 0), cur1 = cur0;
  if (n > 0) {
    int s = csr_src[beg];
    if ((unsigned)s >= (unsigned)Nn) s = 0;
    cur0 = *reinterpret_cast<const ushort4*>(C1 + (size_t)s * 512 + c0);
  }
  if (n > 1) {
    int s = csr_src[beg + 1];
    if ((unsigned)s >= (unsigned)Nn) s = 0;
    cur1 = *reinterpret_cast<const ushort4*>(C1 + (size_t)s * 512 + c0);
  }

#define AGG1_BODY(XV)                                                        \
  {                                                                          \
    float xl0 = b2f(XV.x), xl1 = b2f(XV.y), xl2 = b2f(XV.z), xl3 = b2f(XV.w); \
    float m0 = xl0 + xr0, m1 = xl1 + xr1, m2 = xl2 + xr2, m3 = xl3 + xr3;    \
    float l0 = m0 > 0.f ? m0 : 0.2f * m0;                                    \
    float l1 = m1 > 0.f ? m1 : 0.2f * m1;                                    \
    float l2 = m2 > 0.f ? m2 : 0.2f * m2;                                    \
    float l3 = m3 > 0.f ? m3 : 0.2f * m3;                                    \
    float part = l0 * at0 + l1 * at1 + l2 * at2 + l3 * at3;                  \
    part += __shfl_xor(part, 1, 64);                                         \
    part += __shfl_xor(part, 2, 64);                                         \
    part += __shfl_xor(part, 4, 64);                                         \
    part += __shfl_xor(part, 8, 64);                                         \
    part = fminf(fmaxf(part, -60.f), 60.f);                                  \
    float wgt = __expf(part);                                                \
    denom += wgt;                                                            \
    a0 += wgt * xl0; a1 += wgt * xl1; a2 += wgt * xl2; a3 += wgt * xl3;      \
  }

  int i = 0;
  for (; i + 2 <= n; i += 2) {
    ushort4 nxt0 = cur0, nxt1 = cur1;
    int q0 = beg + i + 2, q1 = beg + i + 3;
    if (q0 < end) {
      int s = csr_src[q0];
      if ((unsigned)s >= (unsigned)Nn) s = 0;
      nxt0 = *reinterpret_cast<const ushort4*>(C1 + (size_t)s * 512 + c0);
    }
    if (q1 < end) {
      int s = csr_src[q1];
      if ((unsigned)s >= (unsigned)Nn) s = 0;
      nxt1 = *reinterpret_cast<const ushort4*>(C1 + (size_t)s * 512 + c0);
    }
    AGG1_BODY(cur0);
    AGG1_BODY(cur1);
    cur0 = nxt0;
    cur1 = nxt1;
  }
  if (i < n) AGG1_BODY(cur0);
#undef AGG1_BODY

  float inv = 1.f / (denom + 1e-16f);
  ushort4 b4 = *reinterpret_cast<const ushort4*>(bias1 + c0);
  float h0 = tanhf(a0 * inv + b2f(b4.x));
  float h1 = tanhf(a1 * inv + b2f(b4.y));
  float h2 = tanhf(a2 * inv + b2f(b4.z));
  float h3 = tanhf(a3 * inv + b2f(b4.w));
  if (!(h0 == h0)) h0 = 0.f;
  if (!(h1 == h1)) h1 = 0.f;
  if (!(h2 == h2)) h2 = 0.f;
  if (!(h3 == h3)) h3 = 0.f;
  ushort4 o4;
  o4.x = f2b(h0); o4.y = f2b(h1); o4.z = f2b(h2); o4.w = f2b(h3);
  *reinterpret_cast<ushort4*>(H1 + (size_t)wid * 256 + c0) = o4;
}

// ---------------- layer-2 aggregation (direct exp, prefetch) + log_softmax ----------------
__global__ __launch_bounds__(256) void agg2_kernel(
    const float* __restrict__ C2,             // [N,32]: 0-15 xl2, 16-31 xr2
    const unsigned short* __restrict__ att2,  // [16]
    const unsigned short* __restrict__ bias2, // [16]
    const int* __restrict__ row_start, const int* __restrict__ csr_src,
    float* __restrict__ out,                  // [2*N*16] f32 (o, log_softmax)
    int Nn, int Etot) {
  int wid = blockIdx.x * 4 + (threadIdx.x >> 6);
  if (wid >= Nn) return;
  int lane = threadIdx.x & 63;
  int g = lane >> 4;
  int c = lane & 15;

  float att = b2f(att2[c]);
  float xr = C2[(size_t)wid * 32 + 16 + c];
  float denom = 0.f, acc = 0.f;
  int beg = row_start[wid], end = row_start[wid + 1];
  if (beg < 0) beg = 0;
  if (end < beg || end - beg > Etot) end = beg;

  int p = beg + g;
  float xl_cur = 0.f;
  if (p < end) {
    int s = csr_src[p];
    if ((unsigned)s >= (unsigned)Nn) s = 0;
    xl_cur = C2[(size_t)s * 32 + c];
  }
  while (p < end) {
    int pn = p + 4;
    float xl_nxt = 0.f;
    if (pn < end) {
      int s = csr_src[pn];
      if ((unsigned)s >= (unsigned)Nn) s = 0;
      xl_nxt = C2[(size_t)s * 32 + c];
    }
    float mm = xl_cur + xr;
    float lr = mm > 0.f ? mm : 0.2f * mm;
    float part = lr * att;
    part += __shfl_xor(part, 1, 64);
    part += __shfl_xor(part, 2, 64);
    part += __shfl_xor(part, 4, 64);
    part += __shfl_xor(part, 8, 64);
    part = fminf(fmaxf(part, -60.f), 60.f);
    float wgt = __expf(part);
    denom += wgt;
    acc += wgt * xl_cur;
    xl_cur = xl_nxt;
    p = pn;
  }
  denom += __shfl_xor(denom, 16, 64);
  denom += __shfl_xor(denom, 32, 64);
  acc += __shfl_xor(acc, 16, 64);
  acc += __shfl_xor(acc, 32, 64);

  float o = acc / (denom + 1e-16f) + b2f(bias2[c]);
  if (!(o == o)) o = 0.f;
  float mx = o;
  mx = fmaxf(mx, __shfl_xor(mx, 1, 64));
  mx = fmaxf(mx, __shfl_xor(mx, 2, 64));
  mx = fmaxf(mx, __shfl_xor(mx, 4, 64));
  mx = fmaxf(mx, __shfl_xor(mx, 8, 64));
  float ex = expf(o - mx);
  float se = ex;
  se += __shfl_xor(se, 1, 64);
  se += __shfl_xor(se, 2, 64);
  se += __shfl_xor(se, 4, 64);
  se += __shfl_xor(se, 8, 64);
  float ls = logf(se);
  if (lane < 16) {
    out[(size_t)wid * 16 + c] = o;
    out[(size_t)Nn * 16 + (size_t)wid * 16 + c] = o - mx - ls;
  }
}

extern "C" void kernel_launch(void* const* d_in, const int* in_sizes, int n_in,
                              void* d_out, int out_size, void* d_ws, size_t ws_size,
                              hipStream_t stream) {
  const void* x_raw = d_in[0];
  const int* ei     = (const int*)d_in[1];

  const int M = in_sizes[0] / 256;  // nodes (50000)
  const int E = in_sizes[1] / 2;    // raw edges (400000)
  const int TOT = E + M;            // edges incl. self-loops

  char* ws = (char*)d_ws;
  size_t off = 0;
  auto alloc = [&](size_t bytes) -> void* {
    void* p = ws + off;
    off = (off + bytes + 255) & ~(size_t)255;
    return p;
  };
  int*            flag   = (int*)alloc(4);
  unsigned short* Pc     = (unsigned short*)alloc((size_t)P_TOT * 2);
  unsigned short* WT1    = (unsigned short*)alloc((size_t)512 * 256 * 2);
  unsigned short* WT2    = (unsigned short*)alloc((size_t)32 * 256 * 2);
  int*            cnt    = (int*)alloc((size_t)M * 4);
  int*            cursor = (int*)alloc((size_t)M * 4);
  int*            row_start = (int*)alloc((size_t)(M + 1) * 4);
  int*            csr_src   = (int*)alloc((size_t)TOT * 4);
  int*            blkTot = (int*)alloc(64 * 4);
  int*            blkOff = (int*)alloc(64 * 4);
  float*          C2     = (float*)alloc((size_t)M * 32 * 4);
  unsigned short* C1     = (unsigned short*)alloc((size_t)M * 512 * 2);
  unsigned short* H1     = (unsigned short*)alloc((size_t)M * 256 * 2);
  const size_t need = off;
  (void)n_in;

  if (ws_size < need) {
    hipMemsetAsync(d_out, 0, (size_t)out_size * 4, stream);
    return;
  }

  unsigned short* bl1c   = Pc + 65536;
  unsigned short* br1c   = Pc + 131328;
  unsigned short* att1c  = Pc + 131584;
  unsigned short* bias1c = Pc + 131840;
  unsigned short* bl2c   = Pc + 136192;
  unsigned short* br2c   = Pc + 140304;
  unsigned short* att2c  = Pc + 140320;
  unsigned short* bias2c = Pc + 140336;

  hipMemsetAsync(cnt, 0, (size_t)M * 4, stream);

  probe_kernel<<<1, 64, 0, stream>>>((const unsigned short*)x_raw, flag);
  conv_params_kernel<<<(P_TOT + 255) / 256, 256, 0, stream>>>(
      d_in[2], d_in[3], d_in[4], d_in[5], d_in[6], d_in[7], d_in[8], d_in[9],
      d_in[10], d_in[11], d_in[12], d_in[13], Pc, flag);

  transpose_w_kernel<<<(512 * 256 + 32 * 256 + 255) / 256, 256, 0, stream>>>(Pc, WT1, WT2);

  dim3 g1((M + 127) / 128, 4);  // x = m-slabs (consecutive blocks -> distinct slabs)
  gemm1_kernel<<<g1, 256, 0, stream>>>(x_raw, flag, WT1, bl1c, br1c, C1, M);

  count_kernel<<<(TOT + 255) / 256, 256, 0, stream>>>(ei, E, M, cnt);
  int nb = (M + 1023) / 1024;
  scan1_kernel<<<nb, 1024, 0, stream>>>(cnt, row_start, blkTot, M);
  scan2_kernel<<<1, 64, 0, stream>>>(blkTot, blkOff, nb, row_start, M, TOT);
  scan3_kernel<<<nb, 1024, 0, stream>>>(row_start, cursor, blkOff, M);
  fill_kernel<<<(TOT + 255) / 256, 256, 0, stream>>>(ei, E, M, cursor, csr_src);

  agg1_kernel<<<(M + 3) / 4, 256, 0, stream>>>(C1, att1c, bias1c, row_start, csr_src,
                                               H1, M, TOT);

  gemm2_kernel<<<(M + 255) / 256, 256, 0, stream>>>(H1, WT2, bl2c, br2c, C2, M);

  agg2_kernel<<<(M + 3) / 4, 256, 0, stream>>>(C2, att2c, bias2c, row_start, csr_src,
                                               (float*)d_out, M, TOT);
}

// Round 8
// 316.044 us; speedup vs baseline: 1.0872x; 1.0872x over previous
//
#include <hip/hip_runtime.h>

typedef __bf16 bfv8 __attribute__((ext_vector_type(8)));
typedef float f32x4 __attribute__((ext_vector_type(4)));
typedef short shortv8 __attribute__((ext_vector_type(8)));

__device__ __forceinline__ float b2f(unsigned short u) {
  unsigned int v = ((unsigned int)u) << 16;
  float f;
  __builtin_memcpy(&f, &v, 4);
  return f;
}
__device__ __forceinline__ unsigned short f2b(float f) {
  unsigned int u;
  __builtin_memcpy(&u, &f, 4);
  u += 0x7fffu + ((u >> 16) & 1u);
  return (unsigned short)(u >> 16);
}

// ---------------- dtype probe (x): f32-as-bf16 shows ~48% absurd exponents ----
__global__ void probe_kernel(const unsigned short* __restrict__ x, int* __restrict__ flag) {
  int lane = threadIdx.x;  // 64 threads
  int cnt = 0;
  for (int i = lane; i < 4096; i += 64) {
    unsigned int e = (x[i] >> 7) & 0xffu;
    if (e >= 0x86u) cnt++;  // |val| >= 128
  }
#pragma unroll
  for (int off = 1; off < 64; off <<= 1) cnt += __shfl_xor(cnt, off, 64);
  if (lane == 0) *flag = (cnt > 100) ? 1 : 0;
}

// ---------------- canonicalize x to bf16 ----------------
__global__ __launch_bounds__(256) void conv_x_kernel(const void* __restrict__ x,
                                                     unsigned short* __restrict__ dst,
                                                     const int* __restrict__ flagp, int n) {
  int i = (blockIdx.x * 256 + threadIdx.x) * 4;
  if (i >= n) return;
  if (*flagp) {
    float4 f = *reinterpret_cast<const float4*>((const float*)x + i);
    ushort4 o;
    o.x = f2b(f.x); o.y = f2b(f.y); o.z = f2b(f.z); o.w = f2b(f.w);
    *reinterpret_cast<ushort4*>(dst + i) = o;
  } else {
    *reinterpret_cast<ushort4*>(dst + i) =
        *reinterpret_cast<const ushort4*>((const unsigned short*)x + i);
  }
}

// ---------------- canonicalize the 12 float param tensors to bf16 ----------------
// Wl1@0 bl1@65536 Wr1@65792 br1@131328 att1@131584 bias1@131840
// Wl2@132096 bl2@136192 Wr2@136208 br2@140304 att2@140320 bias2@140336  total 140352
#define P_TOT 140352
__global__ __launch_bounds__(256) void conv_params_kernel(
    const void* p0, const void* p1, const void* p2, const void* p3,
    const void* p4, const void* p5, const void* p6, const void* p7,
    const void* p8, const void* p9, const void* p10, const void* p11,
    unsigned short* __restrict__ dst, const int* __restrict__ flagp) {
  int i = blockIdx.x * 256 + threadIdx.x;
  if (i >= P_TOT) return;
  const int offs[13] = {0, 65536, 65792, 131328, 131584, 131840, 132096,
                        136192, 136208, 140304, 140320, 140336, P_TOT};
  const void* ptrs[12] = {p0, p1, p2, p3, p4, p5, p6, p7, p8, p9, p10, p11};
  int flag = *flagp;
  int t = 0;
  while (i >= offs[t + 1]) t++;
  int local = i - offs[t];
  unsigned short v;
  if (flag) v = f2b(((const float*)ptrs[t])[local]);
  else v = ((const unsigned short*)ptrs[t])[local];
  dst[i] = v;
}

// ---------------- merged W transposes: WT1[n][k]=W1[k][n], WT2[n][k]=W2[k][n] ----
__global__ __launch_bounds__(256) void transpose_w_kernel(
    const unsigned short* __restrict__ Pc,
    unsigned short* __restrict__ WT1, unsigned short* __restrict__ WT2) {
  int idx = blockIdx.x * 256 + threadIdx.x;
  if (idx < 512 * 256) {
    int n = idx >> 8, k = idx & 255;
    WT1[idx] = (n < 256) ? Pc[0 + k * 256 + n]               // Wl1
                         : Pc[65792 + k * 256 + (n - 256)];  // Wr1
  } else {
    int j = idx - 512 * 256;
    if (j < 32 * 256) {
      int n = j >> 8, k = j & 255;
      WT2[j] = (n < 16) ? Pc[132096 + k * 16 + n]            // Wl2
                        : Pc[136208 + k * 16 + (n - 16)];    // Wr2
    }
  }
}

// ---------------- GEMM1: C[M,512] = X[M,256] @ [Wl1|Wr1] + bias (bf16 out)
// m97-style: WT n-slab double-buffered in LDS (BK=64, XOR seg-swizzle, bank-
// uniform for both ds_write_b128 and ds_read_b128); only X streams from HBM
// in the K-loop. Epilogue reuses the same LDS for coalesced C stores.
__global__ __launch_bounds__(256) void gemm1_kernel(
    const unsigned short* __restrict__ X,   // bf16 [M,256]
    const unsigned short* __restrict__ WT,  // bf16 [512,256]
    const unsigned short* __restrict__ bl, const unsigned short* __restrict__ br,
    unsigned short* __restrict__ C, int M) {
  __shared__ unsigned short smem[18432];  // 36864B: K-loop 2x8192, epilogue 4x4608
  const int t = threadIdx.x;
  const int lane = t & 63;
  const int w = t >> 6;
  const int quad = lane >> 4;
  const int l16 = lane & 15;
  const int n_blk = blockIdx.x;  // 0..3 (fastest -> 4 siblings share the X slab in L2)
  const int m_base = blockIdx.y * 128 + (w >> 1) * 64;
  const int n_base = n_blk * 128 + (w & 1) * 64;

  // staging unit u = t + 256*i : row=u>>3 (0..127 = n within slab), seg=u&7
  const int st_row = t >> 3;
  const int st_seg = t & 7;
  const unsigned short* wt_base =
      WT + ((size_t)(n_blk * 128 + st_row)) * 256 + st_seg * 8;

  f32x4 acc[4][4];
#pragma unroll
  for (int i = 0; i < 4; i++)
#pragma unroll
    for (int j = 0; j < 4; j++) acc[i][j] = (f32x4){0.f, 0.f, 0.f, 0.f};

  shortv8 st[4];
  // load chunk 0 (each thread 4 units: rows st_row + 32*i)
#pragma unroll
  for (int i = 0; i < 4; i++)
    st[i] = *reinterpret_cast<const shortv8*>(wt_base + (size_t)(32 * i) * 256);
#pragma unroll
  for (int i = 0; i < 4; i++) {
    int row = st_row + 32 * i;
    *reinterpret_cast<shortv8*>(smem + row * 64 + ((st_seg ^ (row & 7)) * 8)) = st[i];
  }
  __syncthreads();

#pragma unroll
  for (int c = 0; c < 4; c++) {
    if (c < 3) {
#pragma unroll
      for (int i = 0; i < 4; i++)
        st[i] = *reinterpret_cast<const shortv8*>(wt_base + (size_t)(32 * i) * 256 +
                                                  (c + 1) * 64);
    }
    const unsigned short* bb = smem + (c & 1) * 8192;
#pragma unroll
    for (int sub = 0; sub < 2; sub++) {
      bfv8 a[4], b[4];
      int seg_r = sub * 4 + quad;  // 0..7
#pragma unroll
      for (int i = 0; i < 4; i++) {
        int row = m_base + 16 * i + l16;
        if (row >= M) row = M - 1;
        a[i] = *reinterpret_cast<const bfv8*>(X + (size_t)row * 256 + c * 64 + sub * 32 +
                                              quad * 8);
      }
#pragma unroll
      for (int j = 0; j < 4; j++) {
        int col = (w & 1) * 64 + 16 * j + l16;  // n within the 128-slab
        b[j] = *reinterpret_cast<const bfv8*>(bb + col * 64 + ((seg_r ^ (col & 7)) * 8));
      }
#pragma unroll
      for (int i = 0; i < 4; i++)
#pragma unroll
        for (int j = 0; j < 4; j++)
          acc[i][j] = __builtin_amdgcn_mfma_f32_16x16x32_bf16(a[i], b[j], acc[i][j], 0, 0, 0);
    }
    if (c < 3) {
      int buf = (c + 1) & 1;
#pragma unroll
      for (int i = 0; i < 4; i++) {
        int row = st_row + 32 * i;
        *reinterpret_cast<shortv8*>(smem + buf * 8192 + row * 64 +
                                    ((st_seg ^ (row & 7)) * 8)) = st[i];
      }
      __syncthreads();
    }
  }

  // epilogue: reuse LDS as 4 x (64x72) bf16 tiles, then coalesced 16B stores.
  __syncthreads();
  unsigned short* lt = smem + w * 4608;
#pragma unroll
  for (int j = 0; j < 4; j++) {
    int col = n_base + 16 * j + l16;
    float bias = (col < 256) ? b2f(bl[col]) : b2f(br[col - 256]);
#pragma unroll
    for (int i = 0; i < 4; i++)
#pragma unroll
      for (int r = 0; r < 4; r++)
        lt[(16 * i + quad * 4 + r) * 72 + 16 * j + l16] = f2b(acc[i][j][r] + bias);
  }
#pragma unroll
  for (int pass = 0; pass < 8; pass++) {
    int row = pass * 8 + (lane >> 3);
    int colg = (lane & 7) * 8;
    shortv8 v = *reinterpret_cast<const shortv8*>(lt + row * 72 + colg);
    int grow = m_base + row;
    if (grow < M)
      *reinterpret_cast<shortv8*>(C + (size_t)grow * 512 + n_base - (w & 1) * 64 +
                                  (w & 1) * 64 + colg) = v;
  }
}

// ---------------- GEMM2: C2[M,32] = H[M,256] @ [Wl2|Wr2] + bias (f32 out)
__global__ __launch_bounds__(256) void gemm2_kernel(
    const unsigned short* __restrict__ H, const unsigned short* __restrict__ WT,
    const unsigned short* __restrict__ bl, const unsigned short* __restrict__ br,
    float* __restrict__ C, int M) {
  const int lane = threadIdx.x & 63;
  const int w = threadIdx.x >> 6;
  const int quad = lane >> 4;
  const int l16 = lane & 15;
  const int m_base = blockIdx.x * 256 + w * 64;

  f32x4 acc[4][2];
#pragma unroll
  for (int i = 0; i < 4; i++)
#pragma unroll
    for (int j = 0; j < 2; j++) acc[i][j] = (f32x4){0.f, 0.f, 0.f, 0.f};

#pragma unroll
  for (int k0 = 0; k0 < 256; k0 += 32) {
    bfv8 a[4], b[2];
#pragma unroll
    for (int i = 0; i < 4; i++) {
      int row = m_base + 16 * i + l16;
      if (row >= M) row = M - 1;
      a[i] = *reinterpret_cast<const bfv8*>(H + (size_t)row * 256 + k0 + quad * 8);
    }
#pragma unroll
    for (int j = 0; j < 2; j++) {
      int col = 16 * j + l16;
      b[j] = *reinterpret_cast<const bfv8*>(WT + (size_t)col * 256 + k0 + quad * 8);
    }
#pragma unroll
    for (int i = 0; i < 4; i++)
#pragma unroll
      for (int j = 0; j < 2; j++)
        acc[i][j] = __builtin_amdgcn_mfma_f32_16x16x32_bf16(a[i], b[j], acc[i][j], 0, 0, 0);
  }

#pragma unroll
  for (int j = 0; j < 2; j++) {
    int col = 16 * j + l16;
    float bias = (j == 0) ? b2f(bl[l16]) : b2f(br[l16]);
#pragma unroll
    for (int i = 0; i < 4; i++) {
#pragma unroll
      for (int r = 0; r < 4; r++) {
        int row = m_base + 16 * i + quad * 4 + r;
        if (row < M) C[(size_t)row * 32 + col] = acc[i][j][r] + bias;
      }
    }
  }
}

// ---------------- CSR build: count + 3-kernel multi-block scan + fill ----------------
__global__ __launch_bounds__(256) void count_kernel(const int* __restrict__ ei, int E, int Nn,
                                                    int* __restrict__ cnt) {
  int i = blockIdx.x * 256 + threadIdx.x;
  int total = E + Nn;
  if (i >= total) return;
  int d = (i < E) ? ei[E + i] : (i - E);
  if ((unsigned)d >= (unsigned)Nn) d = 0;
  atomicAdd(&cnt[d], 1);
}

__global__ __launch_bounds__(1024) void scan1_kernel(const int* __restrict__ cnt,
                                                     int* __restrict__ row_start,
                                                     int* __restrict__ blkTot, int Nn) {
  __shared__ int buf[1024];
  int t = threadIdx.x;
  int i = blockIdx.x * 1024 + t;
  int v = (i < Nn) ? cnt[i] : 0;
  buf[t] = v;
  __syncthreads();
  for (int off = 1; off < 1024; off <<= 1) {
    int x = (t >= off) ? buf[t - off] : 0;
    __syncthreads();
    buf[t] += x;
    __syncthreads();
  }
  if (i < Nn) row_start[i] = buf[t] - v;  // block-local exclusive
  if (t == 1023) blkTot[blockIdx.x] = buf[1023];
}

__global__ __launch_bounds__(64) void scan2_kernel(const int* __restrict__ blkTot,
                                                   int* __restrict__ blkOff, int nb,
                                                   int* __restrict__ row_start, int Nn,
                                                   int total) {
  int lane = threadIdx.x;  // nb <= 64
  int v = (lane < nb) ? blkTot[lane] : 0;
  int s = v;
#pragma unroll
  for (int off = 1; off < 64; off <<= 1) {
    int u = __shfl_up(s, off, 64);
    if (lane >= off) s += u;
  }
  if (lane < nb) blkOff[lane] = s - v;
  if (lane == 0) row_start[Nn] = total;
}

__global__ __launch_bounds__(1024) void scan3_kernel(int* __restrict__ row_start,
                                                     int* __restrict__ cursor,
                                                     const int* __restrict__ blkOff, int Nn) {
  int i = blockIdx.x * 1024 + threadIdx.x;
  if (i < Nn) {
    int val = row_start[i] + blkOff[blockIdx.x];
    row_start[i] = val;
    cursor[i] = val;
  }
}

__global__ __launch_bounds__(256) void fill_kernel(const int* __restrict__ ei, int E, int Nn,
                                                   int* __restrict__ cursor,
                                                   int* __restrict__ csr_src) {
  int i = blockIdx.x * 256 + threadIdx.x;
  int total = E + Nn;
  if (i >= total) return;
  int s, d;
  if (i < E) { s = ei[i]; d = ei[E + i]; } else { s = i - E; d = i - E; }
  if ((unsigned)d >= (unsigned)Nn) d = 0;
  if ((unsigned)s >= (unsigned)Nn) s = 0;
  int pos = atomicAdd(&cursor[d], 1);
  if ((unsigned)pos < (unsigned)total) csr_src[pos] = s;
}

// ---------------- layer-1 aggregation (direct exp, 2-deep pipeline) + tanh ----------------
__global__ __launch_bounds__(256) void agg1_kernel(
    const unsigned short* __restrict__ C1,    // [N,512]: 0-255 xl, 256-511 xr
    const unsigned short* __restrict__ att1,  // [256]
    const unsigned short* __restrict__ bias1, // [256]
    const int* __restrict__ row_start, const int* __restrict__ csr_src,
    unsigned short* __restrict__ H1,          // [N,256] bf16
    int Nn, int Etot) {
  int wid = blockIdx.x * 4 + (threadIdx.x >> 6);
  if (wid >= Nn) return;
  int lane = threadIdx.x & 63;
  int c0 = lane * 4;

  ushort4 a4 = *reinterpret_cast<const ushort4*>(att1 + c0);
  float at0 = b2f(a4.x), at1 = b2f(a4.y), at2 = b2f(a4.z), at3 = b2f(a4.w);
  ushort4 r4 = *reinterpret_cast<const ushort4*>(C1 + (size_t)wid * 512 + 256 + c0);
  float xr0 = b2f(r4.x), xr1 = b2f(r4.y), xr2 = b2f(r4.z), xr3 = b2f(r4.w);

  float denom = 0.f, a0 = 0.f, a1 = 0.f, a2 = 0.f, a3 = 0.f;
  int beg = row_start[wid], end = row_start[wid + 1];
  if (beg < 0) beg = 0;
  if (end < beg || end - beg > Etot) end = beg;
  int n = end - beg;

  ushort4 cur0 = make_ushort4(0, 0, 0, 0), cur1 = cur0;
  if (n > 0) {
    int s = csr_src[beg];
    if ((unsigned)s >= (unsigned)Nn) s = 0;
    cur0 = *reinterpret_cast<const ushort4*>(C1 + (size_t)s * 512 + c0);
  }
  if (n > 1) {
    int s = csr_src[beg + 1];
    if ((unsigned)s >= (unsigned)Nn) s = 0;
    cur1 = *reinterpret_cast<const ushort4*>(C1 + (size_t)s * 512 + c0);
  }

#define AGG1_BODY(XV)                                                        \
  {                                                                          \
    float xl0 = b2f(XV.x), xl1 = b2f(XV.y), xl2 = b2f(XV.z), xl3 = b2f(XV.w); \
    float m0 = xl0 + xr0, m1 = xl1 + xr1, m2 = xl2 + xr2, m3 = xl3 + xr3;    \
    float l0 = m0 > 0.f ? m0 : 0.2f * m0;                                    \
    float l1 = m1 > 0.f ? m1 : 0.2f * m1;                                    \
    float l2 = m2 > 0.f ? m2 : 0.2f * m2;                                    \
    float l3 = m3 > 0.f ? m3 : 0.2f * m3;                                    \
    float part = l0 * at0 + l1 * at1 + l2 * at2 + l3 * at3;                  \
    part += __shfl_xor(part, 1, 64);                                         \
    part += __shfl_xor(part, 2, 64);                                         \
    part += __shfl_xor(part, 4, 64);                                         \
    part += __shfl_xor(part, 8, 64);                                         \
    part = fminf(fmaxf(part, -60.f), 60.f);                                  \
    float wgt = __expf(part);                                                \
    denom += wgt;                                                            \
    a0 += wgt * xl0; a1 += wgt * xl1; a2 += wgt * xl2; a3 += wgt * xl3;      \
  }

  int i = 0;
  for (; i + 2 <= n; i += 2) {
    ushort4 nxt0 = cur0, nxt1 = cur1;
    int q0 = beg + i + 2, q1 = beg + i + 3;
    if (q0 < end) {
      int s = csr_src[q0];
      if ((unsigned)s >= (unsigned)Nn) s = 0;
      nxt0 = *reinterpret_cast<const ushort4*>(C1 + (size_t)s * 512 + c0);
    }
    if (q1 < end) {
      int s = csr_src[q1];
      if ((unsigned)s >= (unsigned)Nn) s = 0;
      nxt1 = *reinterpret_cast<const ushort4*>(C1 + (size_t)s * 512 + c0);
    }
    AGG1_BODY(cur0);
    AGG1_BODY(cur1);
    cur0 = nxt0;
    cur1 = nxt1;
  }
  if (i < n) AGG1_BODY(cur0);
#undef AGG1_BODY

  float inv = 1.f / (denom + 1e-16f);
  ushort4 b4 = *reinterpret_cast<const ushort4*>(bias1 + c0);
  float h0 = tanhf(a0 * inv + b2f(b4.x));
  float h1 = tanhf(a1 * inv + b2f(b4.y));
  float h2 = tanhf(a2 * inv + b2f(b4.z));
  float h3 = tanhf(a3 * inv + b2f(b4.w));
  if (!(h0 == h0)) h0 = 0.f;
  if (!(h1 == h1)) h1 = 0.f;
  if (!(h2 == h2)) h2 = 0.f;
  if (!(h3 == h3)) h3 = 0.f;
  ushort4 o4;
  o4.x = f2b(h0); o4.y = f2b(h1); o4.z = f2b(h2); o4.w = f2b(h3);
  *reinterpret_cast<ushort4*>(H1 + (size_t)wid * 256 + c0) = o4;
}

// ---------------- layer-2 aggregation (direct exp, prefetch) + log_softmax ----------------
__global__ __launch_bounds__(256) void agg2_kernel(
    const float* __restrict__ C2,             // [N,32]: 0-15 xl2, 16-31 xr2
    const unsigned short* __restrict__ att2,  // [16]
    const unsigned short* __restrict__ bias2, // [16]
    const int* __restrict__ row_start, const int* __restrict__ csr_src,
    float* __restrict__ out,                  // [2*N*16] f32 (o, log_softmax)
    int Nn, int Etot) {
  int wid = blockIdx.x * 4 + (threadIdx.x >> 6);
  if (wid >= Nn) return;
  int lane = threadIdx.x & 63;
  int g = lane >> 4;
  int c = lane & 15;

  float att = b2f(att2[c]);
  float xr = C2[(size_t)wid * 32 + 16 + c];
  float denom = 0.f, acc = 0.f;
  int beg = row_start[wid], end = row_start[wid + 1];
  if (beg < 0) beg = 0;
  if (end < beg || end - beg > Etot) end = beg;

  int p = beg + g;
  float xl_cur = 0.f;
  if (p < end) {
    int s = csr_src[p];
    if ((unsigned)s >= (unsigned)Nn) s = 0;
    xl_cur = C2[(size_t)s * 32 + c];
  }
  while (p < end) {
    int pn = p + 4;
    float xl_nxt = 0.f;
    if (pn < end) {
      int s = csr_src[pn];
      if ((unsigned)s >= (unsigned)Nn) s = 0;
      xl_nxt = C2[(size_t)s * 32 + c];
    }
    float mm = xl_cur + xr;
    float lr = mm > 0.f ? mm : 0.2f * mm;
    float part = lr * att;
    part += __shfl_xor(part, 1, 64);
    part += __shfl_xor(part, 2, 64);
    part += __shfl_xor(part, 4, 64);
    part += __shfl_xor(part, 8, 64);
    part = fminf(fmaxf(part, -60.f), 60.f);
    float wgt = __expf(part);
    denom += wgt;
    acc += wgt * xl_cur;
    xl_cur = xl_nxt;
    p = pn;
  }
  denom += __shfl_xor(denom, 16, 64);
  denom += __shfl_xor(denom, 32, 64);
  acc += __shfl_xor(acc, 16, 64);
  acc += __shfl_xor(acc, 32, 64);

  float o = acc / (denom + 1e-16f) + b2f(bias2[c]);
  if (!(o == o)) o = 0.f;
  float mx = o;
  mx = fmaxf(mx, __shfl_xor(mx, 1, 64));
  mx = fmaxf(mx, __shfl_xor(mx, 2, 64));
  mx = fmaxf(mx, __shfl_xor(mx, 4, 64));
  mx = fmaxf(mx, __shfl_xor(mx, 8, 64));
  float ex = expf(o - mx);
  float se = ex;
  se += __shfl_xor(se, 1, 64);
  se += __shfl_xor(se, 2, 64);
  se += __shfl_xor(se, 4, 64);
  se += __shfl_xor(se, 8, 64);
  float ls = logf(se);
  if (lane < 16) {
    out[(size_t)wid * 16 + c] = o;
    out[(size_t)Nn * 16 + (size_t)wid * 16 + c] = o - mx - ls;
  }
}

extern "C" void kernel_launch(void* const* d_in, const int* in_sizes, int n_in,
                              void* d_out, int out_size, void* d_ws, size_t ws_size,
                              hipStream_t stream) {
  const void* x_raw = d_in[0];
  const int* ei     = (const int*)d_in[1];

  const int M = in_sizes[0] / 256;  // nodes (50000)
  const int E = in_sizes[1] / 2;    // raw edges (400000)
  const int TOT = E + M;            // edges incl. self-loops
  const int NX = M * 256;

  char* ws = (char*)d_ws;
  size_t off = 0;
  auto alloc = [&](size_t bytes) -> void* {
    void* p = ws + off;
    off = (off + bytes + 255) & ~(size_t)255;
    return p;
  };
  int*            flag   = (int*)alloc(4);
  unsigned short* Pc     = (unsigned short*)alloc((size_t)P_TOT * 2);
  unsigned short* Xc     = (unsigned short*)alloc((size_t)NX * 2);
  unsigned short* WT1    = (unsigned short*)alloc((size_t)512 * 256 * 2);
  unsigned short* WT2    = (unsigned short*)alloc((size_t)32 * 256 * 2);
  int*            cnt    = (int*)alloc((size_t)M * 4);
  int*            cursor = (int*)alloc((size_t)M * 4);
  int*            row_start = (int*)alloc((size_t)(M + 1) * 4);
  int*            csr_src   = (int*)alloc((size_t)TOT * 4);
  int*            blkTot = (int*)alloc(64 * 4);
  int*            blkOff = (int*)alloc(64 * 4);
  float*          C2     = (float*)alloc((size_t)M * 32 * 4);
  unsigned short* C1     = (unsigned short*)alloc((size_t)M * 512 * 2);
  const size_t need = off;
  (void)n_in;
  // H1 aliases Xc: gemm1 is the last reader of Xc; agg1 writes H1 later.
  unsigned short* H1 = Xc;

  if (ws_size < need) {
    hipMemsetAsync(d_out, 0, (size_t)out_size * 4, stream);
    return;
  }

  unsigned short* bl1c   = Pc + 65536;
  unsigned short* br1c   = Pc + 131328;
  unsigned short* att1c  = Pc + 131584;
  unsigned short* bias1c = Pc + 131840;
  unsigned short* bl2c   = Pc + 136192;
  unsigned short* br2c   = Pc + 140304;
  unsigned short* att2c  = Pc + 140320;
  unsigned short* bias2c = Pc + 140336;

  hipMemsetAsync(cnt, 0, (size_t)M * 4, stream);

  probe_kernel<<<1, 64, 0, stream>>>((const unsigned short*)x_raw, flag);
  conv_x_kernel<<<(NX / 4 + 255) / 256, 256, 0, stream>>>(x_raw, Xc, flag, NX);
  conv_params_kernel<<<(P_TOT + 255) / 256, 256, 0, stream>>>(
      d_in[2], d_in[3], d_in[4], d_in[5], d_in[6], d_in[7], d_in[8], d_in[9],
      d_in[10], d_in[11], d_in[12], d_in[13], Pc, flag);

  transpose_w_kernel<<<(512 * 256 + 32 * 256 + 255) / 256, 256, 0, stream>>>(Pc, WT1, WT2);

  dim3 g1(4, (M + 127) / 128);  // n-blocks fastest: 4 siblings share X slab in L2
  gemm1_kernel<<<g1, 256, 0, stream>>>(Xc, WT1, bl1c, br1c, C1, M);

  count_kernel<<<(TOT + 255) / 256, 256, 0, stream>>>(ei, E, M, cnt);
  int nb = (M + 1023) / 1024;
  scan1_kernel<<<nb, 1024, 0, stream>>>(cnt, row_start, blkTot, M);
  scan2_kernel<<<1, 64, 0, stream>>>(blkTot, blkOff, nb, row_start, M, TOT);
  scan3_kernel<<<nb, 1024, 0, stream>>>(row_start, cursor, blkOff, M);
  fill_kernel<<<(TOT + 255) / 256, 256, 0, stream>>>(ei, E, M, cursor, csr_src);

  agg1_kernel<<<(M + 3) / 4, 256, 0, stream>>>(C1, att1c, bias1c, row_start, csr_src,
                                               H1, M, TOT);

  gemm2_kernel<<<(M + 255) / 256, 256, 0, stream>>>(H1, WT2, bl2c, br2c, C2, M);

  agg2_kernel<<<(M + 3) / 4, 256, 0, stream>>>(C2, att2c, bias2c, row_start, csr_src,
                                               (float*)d_out, M, TOT);
}

// Round 9
// 301.642 us; speedup vs baseline: 1.1391x; 1.0477x over previous
//
#include <hip/hip_runtime.h>

typedef __bf16 bfv8 __attribute__((ext_vector_type(8)));
typedef float f32x4 __attribute__((ext_vector_type(4)));
typedef short shortv8 __attribute__((ext_vector_type(8)));
typedef unsigned short usv8 __attribute__((ext_vector_type(8)));

__device__ __forceinline__ float b2f(unsigned short u) {
  unsigned int v = ((unsigned int)u) << 16;
  float f;
  __builtin_memcpy(&f, &v, 4);
  return f;
}
__device__ __forceinline__ unsigned short f2b(float f) {
  unsigned int u;
  __builtin_memcpy(&u, &f, 4);
  u += 0x7fffu + ((u >> 16) & 1u);
  return (unsigned short)(u >> 16);
}

// ---------------- dtype probe (x): f32-as-bf16 shows ~48% absurd exponents ----
__global__ void probe_kernel(const unsigned short* __restrict__ x, int* __restrict__ flag) {
  int lane = threadIdx.x;  // 64 threads
  int cnt = 0;
  for (int i = lane; i < 4096; i += 64) {
    unsigned int e = (x[i] >> 7) & 0xffu;
    if (e >= 0x86u) cnt++;  // |val| >= 128
  }
#pragma unroll
  for (int off = 1; off < 64; off <<= 1) cnt += __shfl_xor(cnt, off, 64);
  if (lane == 0) *flag = (cnt > 100) ? 1 : 0;
}

// ---------------- canonicalize x to bf16 ----------------
__global__ __launch_bounds__(256) void conv_x_kernel(const void* __restrict__ x,
                                                     unsigned short* __restrict__ dst,
                                                     const int* __restrict__ flagp, int n) {
  int i = (blockIdx.x * 256 + threadIdx.x) * 4;
  if (i >= n) return;
  if (*flagp) {
    float4 f = *reinterpret_cast<const float4*>((const float*)x + i);
    ushort4 o;
    o.x = f2b(f.x); o.y = f2b(f.y); o.z = f2b(f.z); o.w = f2b(f.w);
    *reinterpret_cast<ushort4*>(dst + i) = o;
  } else {
    *reinterpret_cast<ushort4*>(dst + i) =
        *reinterpret_cast<const ushort4*>((const unsigned short*)x + i);
  }
}

// ---------------- canonicalize the 12 float param tensors to bf16 ----------------
// Wl1@0 bl1@65536 Wr1@65792 br1@131328 att1@131584 bias1@131840
// Wl2@132096 bl2@136192 Wr2@136208 br2@140304 att2@140320 bias2@140336  total 140352
#define P_TOT 140352
__global__ __launch_bounds__(256) void conv_params_kernel(
    const void* p0, const void* p1, const void* p2, const void* p3,
    const void* p4, const void* p5, const void* p6, const void* p7,
    const void* p8, const void* p9, const void* p10, const void* p11,
    unsigned short* __restrict__ dst, const int* __restrict__ flagp) {
  int i = blockIdx.x * 256 + threadIdx.x;
  if (i >= P_TOT) return;
  const int offs[13] = {0, 65536, 65792, 131328, 131584, 131840, 132096,
                        136192, 136208, 140304, 140320, 140336, P_TOT};
  const void* ptrs[12] = {p0, p1, p2, p3, p4, p5, p6, p7, p8, p9, p10, p11};
  int flag = *flagp;
  int t = 0;
  while (i >= offs[t + 1]) t++;
  int local = i - offs[t];
  unsigned short v;
  if (flag) v = f2b(((const float*)ptrs[t])[local]);
  else v = ((const unsigned short*)ptrs[t])[local];
  dst[i] = v;
}

// ---------------- merged W transposes: WT1[n][k]=W1[k][n], WT2[n][k]=W2[k][n] ----
__global__ __launch_bounds__(256) void transpose_w_kernel(
    const unsigned short* __restrict__ Pc,
    unsigned short* __restrict__ WT1, unsigned short* __restrict__ WT2) {
  int idx = blockIdx.x * 256 + threadIdx.x;
  if (idx < 512 * 256) {
    int n = idx >> 8, k = idx & 255;
    WT1[idx] = (n < 256) ? Pc[0 + k * 256 + n]               // Wl1
                         : Pc[65792 + k * 256 + (n - 256)];  // Wr1
  } else {
    int j = idx - 512 * 256;
    if (j < 32 * 256) {
      int n = j >> 8, k = j & 255;
      WT2[j] = (n < 16) ? Pc[132096 + k * 16 + n]            // Wl2
                        : Pc[136208 + k * 16 + (n - 16)];    // Wr2
    }
  }
}

// ---------------- GEMM1: C[M,512] = X[M,256] @ [Wl1|Wr1] + bias (bf16 out)
// m97-style: WT n-slab double-buffered in LDS (BK=64, XOR seg-swizzle); only X
// streams from HBM in the K-loop. Epilogue reuses LDS for coalesced C stores.
__global__ __launch_bounds__(256) void gemm1_kernel(
    const unsigned short* __restrict__ X,   // bf16 [M,256]
    const unsigned short* __restrict__ WT,  // bf16 [512,256]
    const unsigned short* __restrict__ bl, const unsigned short* __restrict__ br,
    unsigned short* __restrict__ C, int M) {
  __shared__ unsigned short smem[18432];  // 36864B: K-loop 2x8192, epilogue 4x4608
  const int t = threadIdx.x;
  const int lane = t & 63;
  const int w = t >> 6;
  const int quad = lane >> 4;
  const int l16 = lane & 15;
  const int n_blk = blockIdx.x;  // 0..3 fastest -> 4 siblings share the X slab in L2
  const int m_base = blockIdx.y * 128 + (w >> 1) * 64;
  const int n_base = n_blk * 128 + (w & 1) * 64;

  const int st_row = t >> 3;
  const int st_seg = t & 7;
  const unsigned short* wt_base =
      WT + ((size_t)(n_blk * 128 + st_row)) * 256 + st_seg * 8;

  f32x4 acc[4][4];
#pragma unroll
  for (int i = 0; i < 4; i++)
#pragma unroll
    for (int j = 0; j < 4; j++) acc[i][j] = (f32x4){0.f, 0.f, 0.f, 0.f};

  shortv8 st[4];
#pragma unroll
  for (int i = 0; i < 4; i++)
    st[i] = *reinterpret_cast<const shortv8*>(wt_base + (size_t)(32 * i) * 256);
#pragma unroll
  for (int i = 0; i < 4; i++) {
    int row = st_row + 32 * i;
    *reinterpret_cast<shortv8*>(smem + row * 64 + ((st_seg ^ (row & 7)) * 8)) = st[i];
  }
  __syncthreads();

#pragma unroll
  for (int c = 0; c < 4; c++) {
    if (c < 3) {
#pragma unroll
      for (int i = 0; i < 4; i++)
        st[i] = *reinterpret_cast<const shortv8*>(wt_base + (size_t)(32 * i) * 256 +
                                                  (c + 1) * 64);
    }
    const unsigned short* bb = smem + (c & 1) * 8192;
#pragma unroll
    for (int sub = 0; sub < 2; sub++) {
      bfv8 a[4], b[4];
      int seg_r = sub * 4 + quad;  // 0..7
#pragma unroll
      for (int i = 0; i < 4; i++) {
        int row = m_base + 16 * i + l16;
        if (row >= M) row = M - 1;
        a[i] = *reinterpret_cast<const bfv8*>(X + (size_t)row * 256 + c * 64 + sub * 32 +
                                              quad * 8);
      }
#pragma unroll
      for (int j = 0; j < 4; j++) {
        int col = (w & 1) * 64 + 16 * j + l16;  // n within the 128-slab
        b[j] = *reinterpret_cast<const bfv8*>(bb + col * 64 + ((seg_r ^ (col & 7)) * 8));
      }
#pragma unroll
      for (int i = 0; i < 4; i++)
#pragma unroll
        for (int j = 0; j < 4; j++)
          acc[i][j] = __builtin_amdgcn_mfma_f32_16x16x32_bf16(a[i], b[j], acc[i][j], 0, 0, 0);
    }
    if (c < 3) {
      int buf = (c + 1) & 1;
#pragma unroll
      for (int i = 0; i < 4; i++) {
        int row = st_row + 32 * i;
        *reinterpret_cast<shortv8*>(smem + buf * 8192 + row * 64 +
                                    ((st_seg ^ (row & 7)) * 8)) = st[i];
      }
      __syncthreads();
    }
  }

  __syncthreads();
  unsigned short* lt = smem + w * 4608;
#pragma unroll
  for (int j = 0; j < 4; j++) {
    int col = n_base + 16 * j + l16;
    float bias = (col < 256) ? b2f(bl[col]) : b2f(br[col - 256]);
#pragma unroll
    for (int i = 0; i < 4; i++)
#pragma unroll
      for (int r = 0; r < 4; r++)
        lt[(16 * i + quad * 4 + r) * 72 + 16 * j + l16] = f2b(acc[i][j][r] + bias);
  }
#pragma unroll
  for (int pass = 0; pass < 8; pass++) {
    int row = pass * 8 + (lane >> 3);
    int colg = (lane & 7) * 8;
    shortv8 v = *reinterpret_cast<const shortv8*>(lt + row * 72 + colg);
    int grow = m_base + row;
    if (grow < M)
      *reinterpret_cast<shortv8*>(C + (size_t)grow * 512 + n_base + colg) = v;
  }
}

// ---------------- GEMM2: C2[M,32] = H[M,256] @ [Wl2|Wr2] + bias (f32 out)
__global__ __launch_bounds__(256) void gemm2_kernel(
    const unsigned short* __restrict__ H, const unsigned short* __restrict__ WT,
    const unsigned short* __restrict__ bl, const unsigned short* __restrict__ br,
    float* __restrict__ C, int M) {
  const int lane = threadIdx.x & 63;
  const int w = threadIdx.x >> 6;
  const int quad = lane >> 4;
  const int l16 = lane & 15;
  const int m_base = blockIdx.x * 256 + w * 64;

  f32x4 acc[4][2];
#pragma unroll
  for (int i = 0; i < 4; i++)
#pragma unroll
    for (int j = 0; j < 2; j++) acc[i][j] = (f32x4){0.f, 0.f, 0.f, 0.f};

#pragma unroll
  for (int k0 = 0; k0 < 256; k0 += 32) {
    bfv8 a[4], b[2];
#pragma unroll
    for (int i = 0; i < 4; i++) {
      int row = m_base + 16 * i + l16;
      if (row >= M) row = M - 1;
      a[i] = *reinterpret_cast<const bfv8*>(H + (size_t)row * 256 + k0 + quad * 8);
    }
#pragma unroll
    for (int j = 0; j < 2; j++) {
      int col = 16 * j + l16;
      b[j] = *reinterpret_cast<const bfv8*>(WT + (size_t)col * 256 + k0 + quad * 8);
    }
#pragma unroll
    for (int i = 0; i < 4; i++)
#pragma unroll
      for (int j = 0; j < 2; j++)
        acc[i][j] = __builtin_amdgcn_mfma_f32_16x16x32_bf16(a[i], b[j], acc[i][j], 0, 0, 0);
  }

#pragma unroll
  for (int j = 0; j < 2; j++) {
    int col = 16 * j + l16;
    float bias = (j == 0) ? b2f(bl[l16]) : b2f(br[l16]);
#pragma unroll
    for (int i = 0; i < 4; i++) {
#pragma unroll
      for (int r = 0; r < 4; r++) {
        int row = m_base + 16 * i + quad * 4 + r;
        if (row < M) C[(size_t)row * 32 + col] = acc[i][j][r] + bias;
      }
    }
  }
}

// ---------------- CSR build: count + 3-kernel multi-block scan + fill ----------------
__global__ __launch_bounds__(256) void count_kernel(const int* __restrict__ ei, int E, int Nn,
                                                    int* __restrict__ cnt) {
  int i = blockIdx.x * 256 + threadIdx.x;
  int total = E + Nn;
  if (i >= total) return;
  int d = (i < E) ? ei[E + i] : (i - E);
  if ((unsigned)d >= (unsigned)Nn) d = 0;
  atomicAdd(&cnt[d], 1);
}

__global__ __launch_bounds__(1024) void scan1_kernel(const int* __restrict__ cnt,
                                                     int* __restrict__ row_start,
                                                     int* __restrict__ blkTot, int Nn) {
  __shared__ int buf[1024];
  int t = threadIdx.x;
  int i = blockIdx.x * 1024 + t;
  int v = (i < Nn) ? cnt[i] : 0;
  buf[t] = v;
  __syncthreads();
  for (int off = 1; off < 1024; off <<= 1) {
    int x = (t >= off) ? buf[t - off] : 0;
    __syncthreads();
    buf[t] += x;
    __syncthreads();
  }
  if (i < Nn) row_start[i] = buf[t] - v;  // block-local exclusive
  if (t == 1023) blkTot[blockIdx.x] = buf[1023];
}

__global__ __launch_bounds__(64) void scan2_kernel(const int* __restrict__ blkTot,
                                                   int* __restrict__ blkOff, int nb,
                                                   int* __restrict__ row_start, int Nn,
                                                   int total) {
  int lane = threadIdx.x;  // nb <= 64
  int v = (lane < nb) ? blkTot[lane] : 0;
  int s = v;
#pragma unroll
  for (int off = 1; off < 64; off <<= 1) {
    int u = __shfl_up(s, off, 64);
    if (lane >= off) s += u;
  }
  if (lane < nb) blkOff[lane] = s - v;
  if (lane == 0) row_start[Nn] = total;
}

__global__ __launch_bounds__(1024) void scan3_kernel(int* __restrict__ row_start,
                                                     int* __restrict__ cursor,
                                                     const int* __restrict__ blkOff, int Nn) {
  int i = blockIdx.x * 1024 + threadIdx.x;
  if (i < Nn) {
    int val = row_start[i] + blkOff[blockIdx.x];
    row_start[i] = val;
    cursor[i] = val;
  }
}

__global__ __launch_bounds__(256) void fill_kernel(const int* __restrict__ ei, int E, int Nn,
                                                   int* __restrict__ cursor,
                                                   int* __restrict__ csr_src) {
  int i = blockIdx.x * 256 + threadIdx.x;
  int total = E + Nn;
  if (i >= total) return;
  int s, d;
  if (i < E) { s = ei[i]; d = ei[E + i]; } else { s = i - E; d = i - E; }
  if ((unsigned)d >= (unsigned)Nn) d = 0;
  if ((unsigned)s >= (unsigned)Nn) s = 0;
  int pos = atomicAdd(&cursor[d], 1);
  if ((unsigned)pos < (unsigned)total) csr_src[pos] = s;
}

// ---------------- layer-1 aggregation: 2 edges/wave-iteration + tanh ----------------
// lanes 0-31 = edge A, lanes 32-63 = edge B; each lane owns 8 channels
// (c0 = (lane&31)*8). Head = 8-lane group; score reduce = xor {1,2,4}.
// Per-edge wave overhead (exp/clamp/loads/loop) is shared by both halves.
__global__ __launch_bounds__(256) void agg1_kernel(
    const unsigned short* __restrict__ C1,    // [N,512]: 0-255 xl, 256-511 xr
    const unsigned short* __restrict__ att1,  // [256]
    const unsigned short* __restrict__ bias1, // [256]
    const int* __restrict__ row_start, const int* __restrict__ csr_src,
    unsigned short* __restrict__ H1,          // [N,256] bf16
    int Nn, int Etot) {
  int wid = blockIdx.x * 4 + (threadIdx.x >> 6);
  if (wid >= Nn) return;
  int lane = threadIdx.x & 63;
  int half = lane >> 5;
  int c0 = (lane & 31) * 8;

  float at[8], xr[8];
  {
    usv8 a8 = *reinterpret_cast<const usv8*>(att1 + c0);
    usv8 r8 = *reinterpret_cast<const usv8*>(C1 + (size_t)wid * 512 + 256 + c0);
#pragma unroll
    for (int k = 0; k < 8; k++) { at[k] = b2f(a8[k]); xr[k] = b2f(r8[k]); }
  }

  float denom = 0.f;
  float acc[8] = {0.f, 0.f, 0.f, 0.f, 0.f, 0.f, 0.f, 0.f};
  int beg = row_start[wid], end = row_start[wid + 1];
  if (beg < 0) beg = 0;
  if (end < beg || end - beg > Etot) end = beg;

#pragma unroll 2
  for (int i = beg; i < end; i += 2) {
    int p = i + half;
    bool valid = p < end;
    int pc = valid ? p : i;  // i < end guaranteed by loop condition
    int s = csr_src[pc];
    if ((unsigned)s >= (unsigned)Nn) s = 0;
    usv8 row = *reinterpret_cast<const usv8*>(C1 + (size_t)s * 512 + c0);
    float xl[8], dot = 0.f;
#pragma unroll
    for (int k = 0; k < 8; k++) {
      xl[k] = b2f(row[k]);
      float m = xl[k] + xr[k];
      float l = fmaxf(m, 0.2f * m);  // leaky relu
      dot = fmaf(l, at[k], dot);
    }
    dot += __shfl_xor(dot, 1, 64);
    dot += __shfl_xor(dot, 2, 64);
    dot += __shfl_xor(dot, 4, 64);  // head score in all 8 lanes of the group
    dot = fminf(fmaxf(dot, -60.f), 60.f);
    float wgt = valid ? __expf(dot) : 0.f;
    denom += wgt;
#pragma unroll
    for (int k = 0; k < 8; k++) acc[k] = fmaf(wgt, xl[k], acc[k]);
  }
  // merge halves
  denom += __shfl_xor(denom, 32, 64);
#pragma unroll
  for (int k = 0; k < 8; k++) acc[k] += __shfl_xor(acc[k], 32, 64);

  if (half == 0) {
    float inv = 1.f / (denom + 1e-16f);
    usv8 b8 = *reinterpret_cast<const usv8*>(bias1 + c0);
    usv8 o8;
#pragma unroll
    for (int k = 0; k < 8; k++) {
      float x = acc[k] * inv + b2f(b8[k]);
      // tanh via exp: accurate in f32, |x| <= ~15 here
      float e2 = __expf(2.f * x);
      float th = (e2 - 1.f) / (e2 + 1.f);
      if (!(th == th)) th = 0.f;
      o8[k] = f2b(th);
    }
    *reinterpret_cast<usv8*>(H1 + (size_t)wid * 256 + c0) = o8;
  }
}

// ---------------- layer-2 aggregation: 16 edges/wave-iteration + log_softmax ----------------
// edge slot = lane>>2 (16 slots), each lane owns 4 channels (cg = (lane&3)*4).
// Score reduce over slot = xor {1,2}; slot merge = xor {4,8,16,32};
// log-softmax channel reduce = xor {1,2}. Avg degree ~9 -> 1 iteration/node.
__global__ __launch_bounds__(256) void agg2_kernel(
    const float* __restrict__ C2,             // [N,32]: 0-15 xl2, 16-31 xr2
    const unsigned short* __restrict__ att2,  // [16]
    const unsigned short* __restrict__ bias2, // [16]
    const int* __restrict__ row_start, const int* __restrict__ csr_src,
    float* __restrict__ out,                  // [2*N*16] f32 (o, log_softmax)
    int Nn, int Etot) {
  int wid = blockIdx.x * 4 + (threadIdx.x >> 6);
  if (wid >= Nn) return;
  int lane = threadIdx.x & 63;
  int eslot = lane >> 2;
  int cg = (lane & 3) * 4;

  float at[4], xr[4];
  {
    ushort4 a4 = *reinterpret_cast<const ushort4*>(att2 + cg);
    at[0] = b2f(a4.x); at[1] = b2f(a4.y); at[2] = b2f(a4.z); at[3] = b2f(a4.w);
    float4 r4 = *reinterpret_cast<const float4*>(C2 + (size_t)wid * 32 + 16 + cg);
    xr[0] = r4.x; xr[1] = r4.y; xr[2] = r4.z; xr[3] = r4.w;
  }

  float denom = 0.f;
  float acc[4] = {0.f, 0.f, 0.f, 0.f};
  int beg = row_start[wid], end = row_start[wid + 1];
  if (beg < 0) beg = 0;
  if (end < beg || end - beg > Etot) end = beg;

  for (int i = beg; i < end; i += 16) {
    int p = i + eslot;
    bool valid = p < end;
    int pc = valid ? p : i;
    int s = csr_src[pc];
    if ((unsigned)s >= (unsigned)Nn) s = 0;
    float4 x4 = *reinterpret_cast<const float4*>(C2 + (size_t)s * 32 + cg);
    float xl[4] = {x4.x, x4.y, x4.z, x4.w};
    float dot = 0.f;
#pragma unroll
    for (int k = 0; k < 4; k++) {
      float m = xl[k] + xr[k];
      float l = fmaxf(m, 0.2f * m);
      dot = fmaf(l, at[k], dot);
    }
    dot += __shfl_xor(dot, 1, 64);
    dot += __shfl_xor(dot, 2, 64);  // edge score in all 4 lanes of the slot
    dot = fminf(fmaxf(dot, -60.f), 60.f);
    float wgt = valid ? __expf(dot) : 0.f;
    denom += wgt;
#pragma unroll
    for (int k = 0; k < 4; k++) acc[k] = fmaf(wgt, xl[k], acc[k]);
  }
  // merge the 16 edge slots
#pragma unroll
  for (int off = 4; off <= 32; off <<= 1) {
    denom += __shfl_xor(denom, off, 64);
#pragma unroll
    for (int k = 0; k < 4; k++) acc[k] += __shfl_xor(acc[k], off, 64);
  }

  float inv = 1.f / (denom + 1e-16f);
  ushort4 b4 = *reinterpret_cast<const ushort4*>(bias2 + cg);
  float bb[4] = {b2f(b4.x), b2f(b4.y), b2f(b4.z), b2f(b4.w)};
  float o[4];
#pragma unroll
  for (int k = 0; k < 4; k++) {
    o[k] = acc[k] * inv + bb[k];
    if (!(o[k] == o[k])) o[k] = 0.f;
  }
  // log_softmax over 16 channels (4 per lane across 4 channel-lanes)
  float mx = fmaxf(fmaxf(o[0], o[1]), fmaxf(o[2], o[3]));
  mx = fmaxf(mx, __shfl_xor(mx, 1, 64));
  mx = fmaxf(mx, __shfl_xor(mx, 2, 64));
  float se = 0.f;
#pragma unroll
  for (int k = 0; k < 4; k++) se += __expf(o[k] - mx);
  se += __shfl_xor(se, 1, 64);
  se += __shfl_xor(se, 2, 64);
  float ls = logf(se);
  if (lane < 4) {
    float4 vo = {o[0], o[1], o[2], o[3]};
    float4 vl = {o[0] - mx - ls, o[1] - mx - ls, o[2] - mx - ls, o[3] - mx - ls};
    *reinterpret_cast<float4*>(out + (size_t)wid * 16 + cg) = vo;
    *reinterpret_cast<float4*>(out + (size_t)Nn * 16 + (size_t)wid * 16 + cg) = vl;
  }
}

extern "C" void kernel_launch(void* const* d_in, const int* in_sizes, int n_in,
                              void* d_out, int out_size, void* d_ws, size_t ws_size,
                              hipStream_t stream) {
  const void* x_raw = d_in[0];
  const int* ei     = (const int*)d_in[1];

  const int M = in_sizes[0] / 256;  // nodes (50000)
  const int E = in_sizes[1] / 2;    // raw edges (400000)
  const int TOT = E + M;            // edges incl. self-loops
  const int NX = M * 256;

  char* ws = (char*)d_ws;
  size_t off = 0;
  auto alloc = [&](size_t bytes) -> void* {
    void* p = ws + off;
    off = (off + bytes + 255) & ~(size_t)255;
    return p;
  };
  int*            flag   = (int*)alloc(4);
  unsigned short* Pc     = (unsigned short*)alloc((size_t)P_TOT * 2);
  unsigned short* Xc     = (unsigned short*)alloc((size_t)NX * 2);
  unsigned short* WT1    = (unsigned short*)alloc((size_t)512 * 256 * 2);
  unsigned short* WT2    = (unsigned short*)alloc((size_t)32 * 256 * 2);
  int*            cnt    = (int*)alloc((size_t)M * 4);
  int*            cursor = (int*)alloc((size_t)M * 4);
  int*            row_start = (int*)alloc((size_t)(M + 1) * 4);
  int*            csr_src   = (int*)alloc((size_t)TOT * 4);
  int*            blkTot = (int*)alloc(64 * 4);
  int*            blkOff = (int*)alloc(64 * 4);
  float*          C2     = (float*)alloc((size_t)M * 32 * 4);
  unsigned short* C1     = (unsigned short*)alloc((size_t)M * 512 * 2);
  const size_t need = off;
  (void)n_in;
  // H1 aliases Xc: gemm1 is the last reader of Xc; agg1 writes H1 later.
  unsigned short* H1 = Xc;

  if (ws_size < need) {
    hipMemsetAsync(d_out, 0, (size_t)out_size * 4, stream);
    return;
  }

  unsigned short* bl1c   = Pc + 65536;
  unsigned short* br1c   = Pc + 131328;
  unsigned short* att1c  = Pc + 131584;
  unsigned short* bias1c = Pc + 131840;
  unsigned short* bl2c   = Pc + 136192;
  unsigned short* br2c   = Pc + 140304;
  unsigned short* att2c  = Pc + 140320;
  unsigned short* bias2c = Pc + 140336;

  hipMemsetAsync(cnt, 0, (size_t)M * 4, stream);

  probe_kernel<<<1, 64, 0, stream>>>((const unsigned short*)x_raw, flag);
  conv_x_kernel<<<(NX / 4 + 255) / 256, 256, 0, stream>>>(x_raw, Xc, flag, NX);
  conv_params_kernel<<<(P_TOT + 255) / 256, 256, 0, stream>>>(
      d_in[2], d_in[3], d_in[4], d_in[5], d_in[6], d_in[7], d_in[8], d_in[9],
      d_in[10], d_in[11], d_in[12], d_in[13], Pc, flag);

  transpose_w_kernel<<<(512 * 256 + 32 * 256 + 255) / 256, 256, 0, stream>>>(Pc, WT1, WT2);

  dim3 g1(4, (M + 127) / 128);  // n-blocks fastest: 4 siblings share X slab in L2
  gemm1_kernel<<<g1, 256, 0, stream>>>(Xc, WT1, bl1c, br1c, C1, M);

  count_kernel<<<(TOT + 255) / 256, 256, 0, stream>>>(ei, E, M, cnt);
  int nb = (M + 1023) / 1024;
  scan1_kernel<<<nb, 1024, 0, stream>>>(cnt, row_start, blkTot, M);
  scan2_kernel<<<1, 64, 0, stream>>>(blkTot, blkOff, nb, row_start, M, TOT);
  scan3_kernel<<<nb, 1024, 0, stream>>>(row_start, cursor, blkOff, M);
  fill_kernel<<<(TOT + 255) / 256, 256, 0, stream>>>(ei, E, M, cursor, csr_src);

  agg1_kernel<<<(M + 3) / 4, 256, 0, stream>>>(C1, att1c, bias1c, row_start, csr_src,
                                               H1, M, TOT);

  gemm2_kernel<<<(M + 255) / 256, 256, 0, stream>>>(H1, WT2, bl2c, br2c, C2, M);

  agg2_kernel<<<(M + 3) / 4, 256, 0, stream>>>(C2, att2c, bias2c, row_start, csr_src,
                                               (float*)d_out, M, TOT);
}